// Round 2
// baseline (552.332 us; speedup 1.0000x reference)
//
#include <hip/hip_runtime.h>
#include <hip/hip_bf16.h>
#include <cstdint>

using bf16 = __hip_bfloat16;

typedef short s16x8 __attribute__((ext_vector_type(8)));
typedef float f32x4 __attribute__((ext_vector_type(4)));

#define GLDS16(g, l)                                                                   \
  __builtin_amdgcn_global_load_lds((const __attribute__((address_space(1))) void*)(g), \
                                   (__attribute__((address_space(3))) void*)(l), 16, 0, 0)

__device__ __forceinline__ float bf2f(bf16 v) { return __bfloat162float(v); }
__device__ __forceinline__ bf16  f2bf(float v) { return __float2bfloat16(v); }

// ---------------- f32 -> bf16 convert ------------------------------------------------
__global__ void cvt_k(const float* __restrict__ src, bf16* __restrict__ dst, int n)
{
  const int idx = blockIdx.x * 256 + threadIdx.x;
  if (idx < n) dst[idx] = f2bf(src[idx]);
}

// ---------------- zero-pad x_proj_w (f32, 96x2048) to bf16 128x2048 -------------------
__global__ void pad_w_k(const float* __restrict__ w, bf16* __restrict__ wp)
{
  const int idx = blockIdx.x * 256 + threadIdx.x;   // 128*2048
  wp[idx] = (idx < 96 * 2048) ? f2bf(w[idx]) : f2bf(0.f);
}

// ---------------- generic 128x128 MFMA NT-GEMM: C[m,n] = sum_k A[m,k]*W[n,k] ----------
// EPI 0: (unused)   EPI 1: split dt(bf16,ld 64)/BC(f32,ld 32)
// EPI 2: softplus(v+bias[col]) -> f32   EPI 3: f32 store
template <int EPI>
__global__ __launch_bounds__(256, 2) void gemm_nt(
    const bf16* __restrict__ A, const bf16* __restrict__ W,
    void* __restrict__ C0, void* __restrict__ C1, const float* __restrict__ bias,
    int K, int lda, int ldb, int ldc)
{
  __shared__ __align__(16) bf16 As[128 * 32];
  __shared__ __align__(16) bf16 Bs[128 * 32];

  const int tid  = threadIdx.x;
  const int lane = tid & 63;
  const int wave = tid >> 6;
  const int m0 = blockIdx.y * 128;
  const int n0 = blockIdx.x * 128;
  const int wm = (wave >> 1) * 64;   // wave row offset in tile
  const int wn = (wave & 1) * 64;    // wave col offset in tile
  const int fr = lane & 15;
  const int fq = lane >> 4;
  const int srow = tid >> 2;         // staging row 0..63
  const int scol = (tid & 3) * 8;    // staging col chunk

  f32x4 acc[4][4] = {};

  for (int k0 = 0; k0 < K; k0 += 32) {
    __syncthreads();
    GLDS16(A + (size_t)(m0 + srow) * lda + (k0 + scol),      As + tid * 8);
    GLDS16(A + (size_t)(m0 + 64 + srow) * lda + (k0 + scol), As + (tid + 256) * 8);
    GLDS16(W + (size_t)(n0 + srow) * ldb + (k0 + scol),      Bs + tid * 8);
    GLDS16(W + (size_t)(n0 + 64 + srow) * ldb + (k0 + scol), Bs + (tid + 256) * 8);
    __syncthreads();

    s16x8 af[4], wf[4];
#pragma unroll
    for (int i = 0; i < 4; ++i) {
      af[i] = *reinterpret_cast<const s16x8*>(As + (wm + i * 16 + fr) * 32 + fq * 8);
      wf[i] = *reinterpret_cast<const s16x8*>(Bs + (wn + i * 16 + fr) * 32 + fq * 8);
    }
#pragma unroll
    for (int i = 0; i < 4; ++i)
#pragma unroll
      for (int j = 0; j < 4; ++j)
        acc[i][j] = __builtin_amdgcn_mfma_f32_16x16x32_bf16(af[i], wf[j], acc[i][j], 0, 0, 0);
  }

#pragma unroll
  for (int i = 0; i < 4; ++i)
#pragma unroll
    for (int j = 0; j < 4; ++j)
#pragma unroll
      for (int r = 0; r < 4; ++r) {
        const int row = m0 + wm + i * 16 + fq * 4 + r;  // C/D: row=(lane>>4)*4+reg
        const int col = n0 + wn + j * 16 + fr;          //      col=lane&15
        const float v = acc[i][j][r];
        if constexpr (EPI == 1) {
          if (col < 64)      ((bf16*)C0)[(size_t)row * 64 + col] = f2bf(v);
          else if (col < 96) ((float*)C1)[(size_t)row * 32 + (col - 64)] = v;
        } else if constexpr (EPI == 2) {
          const float xb = v + bias[col];
          ((float*)C0)[(size_t)row * ldc + col] =
              fmaxf(xb, 0.f) + log1pf(__expf(-fabsf(xb)));
        } else {
          ((float*)C0)[(size_t)row * ldc + col] = v;
        }
      }
}

// ---------------- depthwise causal conv K=4 + SiLU: xz(f32) -> xc(bf16) ---------------
__global__ void conv_silu_k(const float* __restrict__ xz, const float* __restrict__ cw,
                            bf16* __restrict__ xc)
{
  const int idx = blockIdx.x * 256 + threadIdx.x;   // over B*L*ED = 4M
  const int e  = idx & 2047;
  const int bl = idx >> 11;
  const int l  = bl & 1023;
  const float* xp = xz + (size_t)bl * 4096 + e;     // xp part of xz (cols 0..2047)
  float s = cw[e * 4 + 3] * xp[0];
  if (l >= 1) s += cw[e * 4 + 2] * xp[-4096];
  if (l >= 2) s += cw[e * 4 + 1] * xp[-8192];
  if (l >= 3) s += cw[e * 4 + 0] * xp[-12288];
  xc[idx] = f2bf(s / (1.f + __expf(-s)));
}

// ---------------- fused selective scan + gate: writes u = y * silu(z) (bf16) ----------
// block: 256 threads = 4 waves; wave = 4 e-values x 16 n-lanes; block covers 16 e, 1 b.
__global__ __launch_bounds__(256, 2) void scan_k(
    const float* __restrict__ delta, const float* __restrict__ BC,
    const bf16* __restrict__ xc, const float* __restrict__ xz,
    const float* __restrict__ A_log, const float* __restrict__ Dp,
    bf16* __restrict__ u)
{
  const int tid = threadIdx.x;
  const int b = blockIdx.y;
  const int e0 = blockIdx.x * 16;
  const int wave = tid >> 6, lane = tid & 63;
  const int n = lane & 15, esub = lane >> 4;
  const int e_local = wave * 4 + esub;
  const int e = e0 + e_local;

  __shared__ float sd[64 * 16], sx[64 * 16], sB[64 * 16], sC[64 * 16], sz[64 * 16];
  __shared__ bf16 su[64 * 16];

  const float A_en = -__expf(A_log[e * 16 + n]);
  const float D_e = Dp[e];
  float h = 0.f;

  for (int c = 0; c < 16; ++c) {
    const int l0 = c * 64;
    for (int i = tid; i < 1024; i += 256) {
      const int ll = i >> 4, ee = i & 15;
      const size_t row = (size_t)b * 1024 + l0 + ll;
      sd[i] = delta[row * 2048 + e0 + ee];
      sx[i] = bf2f(xc[row * 2048 + e0 + ee]);
      sz[i] = xz[row * 4096 + 2048 + e0 + ee];
    }
    for (int i = tid; i < 2048; i += 256) {
      const int ll = i >> 5, f = i & 31;
      const size_t row = (size_t)b * 1024 + l0 + ll;
      const float v = BC[row * 32 + f];
      if (f < 16) sB[ll * 16 + f] = v;
      else        sC[ll * 16 + (f - 16)] = v;
    }
    __syncthreads();
#pragma unroll 4
    for (int l = 0; l < 64; ++l) {
      const float dv  = sd[l * 16 + e_local];
      const float xcv = sx[l * 16 + e_local];
      const float dA = __expf(dv * A_en);
      h = fmaf(dA, h, dv * sB[l * 16 + n] * xcv);
      float y = h * sC[l * 16 + n];
      y += __shfl_xor(y, 1, 16);
      y += __shfl_xor(y, 2, 16);
      y += __shfl_xor(y, 4, 16);
      y += __shfl_xor(y, 8, 16);
      if (n == 0) {
        const float zv = sz[l * 16 + e_local];
        su[l * 16 + e_local] = f2bf((y + D_e * xcv) * (zv / (1.f + __expf(-zv))));
      }
    }
    __syncthreads();
    for (int i = tid; i < 1024; i += 256) {
      const int ll = i >> 4, ee = i & 15;
      const size_t row = (size_t)b * 1024 + l0 + ll;
      u[row * 2048 + e0 + ee] = su[i];
    }
  }
}

extern "C" void kernel_launch(void* const* d_in, const int* in_sizes, int n_in,
                              void* d_out, int out_size, void* d_ws, size_t ws_size,
                              hipStream_t stream)
{
  (void)in_sizes; (void)n_in; (void)out_size; (void)ws_size;
  const float* x        = (const float*)d_in[0];   // (2,1024,1024)
  const float* in_proj  = (const float*)d_in[1];   // (4096,1024)
  const float* conv_w   = (const float*)d_in[2];   // (2048,1,4)
  const float* x_proj   = (const float*)d_in[3];   // (96,2048)
  const float* dt_proj  = (const float*)d_in[4];   // (2048,64)
  const float* dt_bias  = (const float*)d_in[5];   // (2048,)
  const float* A_log    = (const float*)d_in[6];   // (2048,16)
  const float* Dp       = (const float*)d_in[7];   // (2048,)
  const float* out_proj = (const float*)d_in[8];   // (1024,2048)

  char* ws = (char*)d_ws;                          // ~85.2 MB used
  float* xz     = (float*)(ws);                    // 2048 x 4096 f32 (xp | z)
  bf16*  xc     = (bf16*) (ws + 33554432);         // 2048 x 2048 bf16
  bf16*  dt     = (bf16*) (ws + 41943040);         // 2048 x 64 bf16
  float* BC     = (float*)(ws + 42205184);         // 2048 x 32 f32 (Bm|Cm)
  float* delta  = (float*)(ws + 42467328);         // 2048 x 2048 f32
  bf16*  u      = (bf16*) (ws + 59244544);         // 2048 x 2048 bf16
  bf16*  wpad   = (bf16*) (ws + 67633152);         // 128 x 2048 bf16
  bf16*  x_bf   = (bf16*) (ws + 68157440);         // 2048 x 1024 bf16
  bf16*  w1_bf  = (bf16*) (ws + 72351744);         // 4096 x 1024 bf16
  bf16*  wo_bf  = (bf16*) (ws + 80740352);         // 1024 x 2048 bf16
  bf16*  dtw_bf = (bf16*) (ws + 84934656);         // 2048 x 64 bf16

  dim3 blk(256);

  // f32 -> bf16 conversions for MFMA operands
  cvt_k<<<dim3(8192),  blk, 0, stream>>>(x,        x_bf,   2048 * 1024);
  cvt_k<<<dim3(16384), blk, 0, stream>>>(in_proj,  w1_bf,  4096 * 1024);
  cvt_k<<<dim3(8192),  blk, 0, stream>>>(out_proj, wo_bf,  1024 * 2048);
  cvt_k<<<dim3(512),   blk, 0, stream>>>(dt_proj,  dtw_bf, 2048 * 64);
  pad_w_k<<<dim3(1024), blk, 0, stream>>>(x_proj, wpad);

  // GEMM1: xz = x @ in_proj^T   (f32 out)
  gemm_nt<3><<<dim3(32, 16), blk, 0, stream>>>(x_bf, w1_bf, xz, nullptr, nullptr,
                                               1024, 1024, 1024, 4096);
  // conv + silu -> xc (bf16)
  conv_silu_k<<<dim3(16384), blk, 0, stream>>>(xz, conv_w, xc);
  // GEMM2: dBC = xc @ x_proj^T  (split into dt bf16 / BC f32)
  gemm_nt<1><<<dim3(1, 16), blk, 0, stream>>>(xc, wpad, dt, BC, nullptr,
                                              2048, 2048, 2048, 0);
  // GEMM3: delta = softplus(dt @ dt_proj^T + b)  (f32)
  gemm_nt<2><<<dim3(16, 16), blk, 0, stream>>>(dt, dtw_bf, delta, nullptr, dt_bias,
                                               64, 64, 64, 2048);
  // fused scan + gate -> u (bf16)
  scan_k<<<dim3(128, 2), blk, 0, stream>>>(delta, BC, xc, xz, A_log, Dp, u);
  // GEMM4: out = u @ out_proj^T  (f32 out)
  gemm_nt<3><<<dim3(8, 16), blk, 0, stream>>>(u, wo_bf, (float*)d_out, nullptr, nullptr,
                                              2048, 2048, 2048, 1024);
}

// Round 3
// 300.024 us; speedup vs baseline: 1.8410x; 1.8410x over previous
//
#include <hip/hip_runtime.h>
#include <hip/hip_bf16.h>
#include <cstdint>

using bf16 = __hip_bfloat16;

typedef short s16x8 __attribute__((ext_vector_type(8)));
typedef float f32x4 __attribute__((ext_vector_type(4)));

#define GLDS16(g, l)                                                                   \
  __builtin_amdgcn_global_load_lds((const __attribute__((address_space(1))) void*)(g), \
                                   (__attribute__((address_space(3))) void*)(l), 16, 0, 0)

__device__ __forceinline__ float bf2f(bf16 v) { return __bfloat162float(v); }
__device__ __forceinline__ bf16  f2bf(float v) { return __float2bfloat16(v); }

#define NC 32   // scan chunks over L
#define CL 32   // chunk length (NC*CL = 1024 = L)

// ---------------- f32 -> bf16 convert ------------------------------------------------
__global__ void cvt_k(const float* __restrict__ src, bf16* __restrict__ dst, int n)
{
  const int idx = blockIdx.x * 256 + threadIdx.x;
  if (idx < n) dst[idx] = f2bf(src[idx]);
}

// ---------------- zero-pad x_proj_w (f32, 96x2048) to bf16 128x2048 -------------------
__global__ void pad_w_k(const float* __restrict__ w, bf16* __restrict__ wp)
{
  const int idx = blockIdx.x * 256 + threadIdx.x;   // 128*2048
  wp[idx] = (idx < 96 * 2048) ? f2bf(w[idx]) : f2bf(0.f);
}

// ---------------- generic 128x128 MFMA NT-GEMM: C[m,n] = sum_k A[m,k]*W[n,k] ----------
// K param = per-block K length; blockIdx.z selects K-slice (split-K).
// EPI 1: split dt(bf16,ld 64)/BC(f32,ld 32)  EPI 2: softplus(v+bias[col]) -> f32
// EPI 3: f32 store                           EPI 4: f32 atomicAdd (split-K)
template <int EPI>
__global__ __launch_bounds__(256, 2) void gemm_nt(
    const bf16* __restrict__ A, const bf16* __restrict__ W,
    void* __restrict__ C0, void* __restrict__ C1, const float* __restrict__ bias,
    int K, int lda, int ldb, int ldc)
{
  __shared__ __align__(16) bf16 As[128 * 32];
  __shared__ __align__(16) bf16 Bs[128 * 32];

  const int tid  = threadIdx.x;
  const int lane = tid & 63;
  const int wave = tid >> 6;
  const int m0 = blockIdx.y * 128;
  const int n0 = blockIdx.x * 128;
  const int kbase = blockIdx.z * K;
  const int wm = (wave >> 1) * 64;
  const int wn = (wave & 1) * 64;
  const int fr = lane & 15;
  const int fq = lane >> 4;
  const int srow = tid >> 2;
  const int scol = (tid & 3) * 8;

  f32x4 acc[4][4] = {};

  for (int k0 = kbase; k0 < kbase + K; k0 += 32) {
    __syncthreads();
    GLDS16(A + (size_t)(m0 + srow) * lda + (k0 + scol),      As + tid * 8);
    GLDS16(A + (size_t)(m0 + 64 + srow) * lda + (k0 + scol), As + (tid + 256) * 8);
    GLDS16(W + (size_t)(n0 + srow) * ldb + (k0 + scol),      Bs + tid * 8);
    GLDS16(W + (size_t)(n0 + 64 + srow) * ldb + (k0 + scol), Bs + (tid + 256) * 8);
    __syncthreads();

    s16x8 af[4], wf[4];
#pragma unroll
    for (int i = 0; i < 4; ++i) {
      af[i] = *reinterpret_cast<const s16x8*>(As + (wm + i * 16 + fr) * 32 + fq * 8);
      wf[i] = *reinterpret_cast<const s16x8*>(Bs + (wn + i * 16 + fr) * 32 + fq * 8);
    }
#pragma unroll
    for (int i = 0; i < 4; ++i)
#pragma unroll
      for (int j = 0; j < 4; ++j)
        acc[i][j] = __builtin_amdgcn_mfma_f32_16x16x32_bf16(af[i], wf[j], acc[i][j], 0, 0, 0);
  }

#pragma unroll
  for (int i = 0; i < 4; ++i)
#pragma unroll
    for (int j = 0; j < 4; ++j)
#pragma unroll
      for (int r = 0; r < 4; ++r) {
        const int row = m0 + wm + i * 16 + fq * 4 + r;
        const int col = n0 + wn + j * 16 + fr;
        const float v = acc[i][j][r];
        if constexpr (EPI == 1) {
          if (col < 64)      ((bf16*)C0)[(size_t)row * 64 + col] = f2bf(v);
          else if (col < 96) ((float*)C1)[(size_t)row * 32 + (col - 64)] = v;
        } else if constexpr (EPI == 2) {
          const float xb = v + bias[col];
          ((float*)C0)[(size_t)row * ldc + col] =
              fmaxf(xb, 0.f) + log1pf(__expf(-fabsf(xb)));
        } else if constexpr (EPI == 3) {
          ((float*)C0)[(size_t)row * ldc + col] = v;
        } else {
          atomicAdd((float*)C0 + (size_t)row * ldc + col, v);
        }
      }
}

// ---------------- dBC (f32 2048x128) -> dt bf16 [2048][64] + BC f32 [2048][32] --------
__global__ void dbc_split_k(const float* __restrict__ dBC, bf16* __restrict__ dt,
                            float* __restrict__ BC)
{
  const int idx = blockIdx.x * 256 + threadIdx.x;   // 2048*128
  const int row = idx >> 7, col = idx & 127;
  const float v = dBC[idx];
  if (col < 64)      dt[row * 64 + col] = f2bf(v);
  else if (col < 96) BC[row * 32 + (col - 64)] = v;
}

// ---------------- depthwise causal conv K=4 + SiLU: xz(f32) -> xc(bf16) ---------------
__global__ void conv_silu_k(const float* __restrict__ xz, const float* __restrict__ cw,
                            bf16* __restrict__ xc)
{
  const int idx = blockIdx.x * 256 + threadIdx.x;   // over B*L*ED = 4M
  const int e  = idx & 2047;
  const int bl = idx >> 11;
  const int l  = bl & 1023;
  const float* xp = xz + (size_t)bl * 4096 + e;
  float s = cw[e * 4 + 3] * xp[0];
  if (l >= 1) s += cw[e * 4 + 2] * xp[-4096];
  if (l >= 2) s += cw[e * 4 + 1] * xp[-8192];
  if (l >= 3) s += cw[e * 4 + 0] * xp[-12288];
  xc[idx] = f2bf(s / (1.f + __expf(-s)));
}

// ---------------- scan phase A: per-chunk P[n], q[n] (lane = one channel e) -----------
// grid (ED/256, B, NC); thread owns e, scans CL steps with h[16] in regs.
__global__ __launch_bounds__(256) void scan_pq(
    const float* __restrict__ delta, const float* __restrict__ BC,
    const bf16* __restrict__ xc, const float* __restrict__ A_log,
    float* __restrict__ Pbuf, float* __restrict__ Qbuf)
{
  const int tid = threadIdx.x;
  const int e = blockIdx.x * 256 + tid;
  const int b = blockIdx.y;
  const int c = blockIdx.z;
  const int l0 = c * CL;

  __shared__ float sB[CL * 16];
  for (int i = tid; i < CL * 16; i += 256)
    sB[i] = BC[((size_t)b * 1024 + l0 + (i >> 4)) * 32 + (i & 15)];
  __syncthreads();

  float a2[16], h[16];
#pragma unroll
  for (int n = 0; n < 16; ++n) {
    a2[n] = -__expf(A_log[e * 16 + n]) * 1.44269504f;
    h[n] = 0.f;
  }
  float sumdv = 0.f;

  for (int sub = 0; sub < CL / 16; ++sub) {
    float dreg[16], xreg[16];
#pragma unroll
    for (int tt = 0; tt < 16; ++tt) {
      const size_t row = (size_t)b * 1024 + l0 + sub * 16 + tt;
      dreg[tt] = delta[row * 2048 + e];
      xreg[tt] = bf2f(xc[row * 2048 + e]);
    }
#pragma unroll
    for (int tt = 0; tt < 16; ++tt) {
      const float dv = dreg[tt];
      const float bx = dv * xreg[tt];
      sumdv += dv;
      const int t = sub * 16 + tt;
#pragma unroll
      for (int n = 0; n < 16; ++n)
        h[n] = fmaf(exp2f(dv * a2[n]), h[n], bx * sB[t * 16 + n]);
    }
  }

  const size_t base = (((size_t)b * NC + c) * 2048 + e) * 16;
#pragma unroll
  for (int n = 0; n < 16; ++n) {
    Pbuf[base + n] = exp2f(a2[n] * sumdv);
    Qbuf[base + n] = h[n];
  }
}

// ---------------- scan phase B: sequential combine over NC chunks ---------------------
// 65536 threads; thread = (b, e, n); writes h at chunk start into Hin.
__global__ __launch_bounds__(256) void scan_chain(
    const float* __restrict__ Pbuf, const float* __restrict__ Qbuf,
    float* __restrict__ Hin)
{
  const int idx = blockIdx.x * 256 + threadIdx.x;   // (b*2048+e)*16+n
  const int b = idx >> 15;
  const int rem = idx & 32767;
  float h = 0.f;
  for (int c = 0; c < NC; ++c) {
    const size_t base = ((size_t)(b * NC + c)) * 32768 + rem;
    Hin[base] = h;
    h = fmaf(Pbuf[base], h, Qbuf[base]);
  }
}

// ---------------- scan phase C: recompute chunk scan from Hin, emit u -----------------
__global__ __launch_bounds__(256) void scan_y(
    const float* __restrict__ delta, const float* __restrict__ BC,
    const bf16* __restrict__ xc, const float* __restrict__ xz,
    const float* __restrict__ A_log, const float* __restrict__ Dp,
    const float* __restrict__ Hin, bf16* __restrict__ u)
{
  const int tid = threadIdx.x;
  const int e = blockIdx.x * 256 + tid;
  const int b = blockIdx.y;
  const int c = blockIdx.z;
  const int l0 = c * CL;

  __shared__ float sBC[CL * 32];
  for (int i = tid; i < CL * 32; i += 256)
    sBC[i] = BC[((size_t)b * 1024 + l0 + (i >> 5)) * 32 + (i & 31)];
  __syncthreads();

  float a2[16], h[16];
  const size_t hbase = (((size_t)b * NC + c) * 2048 + e) * 16;
#pragma unroll
  for (int n = 0; n < 16; ++n) {
    a2[n] = -__expf(A_log[e * 16 + n]) * 1.44269504f;
    h[n] = Hin[hbase + n];
  }
  const float D_e = Dp[e];

  for (int sub = 0; sub < CL / 16; ++sub) {
    float dreg[16], xreg[16], zreg[16];
#pragma unroll
    for (int tt = 0; tt < 16; ++tt) {
      const size_t row = (size_t)b * 1024 + l0 + sub * 16 + tt;
      dreg[tt] = delta[row * 2048 + e];
      xreg[tt] = bf2f(xc[row * 2048 + e]);
      zreg[tt] = xz[row * 4096 + 2048 + e];
    }
#pragma unroll
    for (int tt = 0; tt < 16; ++tt) {
      const float dv = dreg[tt];
      const float xcv = xreg[tt];
      const float bx = dv * xcv;
      const int t = sub * 16 + tt;
      float y0 = 0.f, y1 = 0.f, y2 = 0.f, y3 = 0.f;
#pragma unroll
      for (int n = 0; n < 16; ++n) {
        h[n] = fmaf(exp2f(dv * a2[n]), h[n], bx * sBC[t * 32 + n]);
        const float cv = sBC[t * 32 + 16 + n];
        if ((n & 3) == 0)      y0 = fmaf(h[n], cv, y0);
        else if ((n & 3) == 1) y1 = fmaf(h[n], cv, y1);
        else if ((n & 3) == 2) y2 = fmaf(h[n], cv, y2);
        else                   y3 = fmaf(h[n], cv, y3);
      }
      const float y = ((y0 + y1) + (y2 + y3)) + D_e * xcv;
      const float zv = zreg[tt];
      const size_t row = (size_t)b * 1024 + l0 + t;
      u[row * 2048 + e] = f2bf(y * (zv / (1.f + __expf(-zv))));
    }
  }
}

extern "C" void kernel_launch(void* const* d_in, const int* in_sizes, int n_in,
                              void* d_out, int out_size, void* d_ws, size_t ws_size,
                              hipStream_t stream)
{
  (void)in_sizes; (void)n_in; (void)ws_size;
  const float* x        = (const float*)d_in[0];   // (2,1024,1024)
  const float* in_proj  = (const float*)d_in[1];   // (4096,1024)
  const float* conv_w   = (const float*)d_in[2];   // (2048,1,4)
  const float* x_proj   = (const float*)d_in[3];   // (96,2048)
  const float* dt_proj  = (const float*)d_in[4];   // (2048,64)
  const float* dt_bias  = (const float*)d_in[5];   // (2048,)
  const float* A_log    = (const float*)d_in[6];   // (2048,16)
  const float* Dp       = (const float*)d_in[7];   // (2048,)
  const float* out_proj = (const float*)d_in[8];   // (1024,2048)

  char* ws = (char*)d_ws;                          // ~98.3 MB used
  float* xz     = (float*)(ws);                    // 2048 x 4096 f32 (xp | z)
  bf16*  xc     = (bf16*) (ws + 33554432);         // 2048 x 2048 bf16
  bf16*  dt     = (bf16*) (ws + 41943040);         // 2048 x 64 bf16
  float* BC     = (float*)(ws + 42205184);         // 2048 x 32 f32 (Bm|Cm)
  float* delta  = (float*)(ws + 42467328);         // 2048 x 2048 f32
  bf16*  u      = (bf16*) (ws + 59244544);         // 2048 x 2048 bf16
  bf16*  wpad   = (bf16*) (ws + 67633152);         // 128 x 2048 bf16
  bf16*  x_bf   = (bf16*) (ws + 68157440);         // 2048 x 1024 bf16 (dead after GEMM1)
  bf16*  w1_bf  = (bf16*) (ws + 72351744);         // 4096 x 1024 bf16 (dead after GEMM1)
  bf16*  wo_bf  = (bf16*) (ws + 80740352);         // 1024 x 2048 bf16
  bf16*  dtw_bf = (bf16*) (ws + 84934656);         // 2048 x 64 bf16
  float* dBCf   = (float*)(ws + 85196800);         // 2048 x 128 f32 (split-K accum)
  float* Pbuf   = (float*)(ws + 68157440);         // 8 MB, overlays x_bf/w1_bf
  float* Qbuf   = (float*)(ws + 86245376);         // 8 MB
  float* Hin    = (float*)(ws + 94633984);         // 8 MB (end: 103022592)

  dim3 blk(256);

  // zero the split-K accumulators (ws/d_out are re-poisoned to 0xAA each launch)
  hipMemsetAsync(dBCf, 0, 2048 * 128 * 4, stream);
  hipMemsetAsync(d_out, 0, (size_t)out_size * 4, stream);

  // f32 -> bf16 conversions for MFMA operands
  cvt_k<<<dim3(8192),  blk, 0, stream>>>(x,        x_bf,   2048 * 1024);
  cvt_k<<<dim3(16384), blk, 0, stream>>>(in_proj,  w1_bf,  4096 * 1024);
  cvt_k<<<dim3(8192),  blk, 0, stream>>>(out_proj, wo_bf,  1024 * 2048);
  cvt_k<<<dim3(512),   blk, 0, stream>>>(dt_proj,  dtw_bf, 2048 * 64);
  pad_w_k<<<dim3(1024), blk, 0, stream>>>(x_proj, wpad);

  // GEMM1: xz = x @ in_proj^T   (f32 out)
  gemm_nt<3><<<dim3(32, 16, 1), blk, 0, stream>>>(x_bf, w1_bf, xz, nullptr, nullptr,
                                                  1024, 1024, 1024, 4096);
  // conv + silu -> xc (bf16)
  conv_silu_k<<<dim3(16384), blk, 0, stream>>>(xz, conv_w, xc);
  // GEMM2 (split-K x8): dBCf += xc @ wpad^T
  gemm_nt<4><<<dim3(1, 16, 8), blk, 0, stream>>>(xc, wpad, dBCf, nullptr, nullptr,
                                                 256, 2048, 2048, 128);
  dbc_split_k<<<dim3(1024), blk, 0, stream>>>(dBCf, dt, BC);
  // GEMM3: delta = softplus(dt @ dt_proj^T + b)  (f32)
  gemm_nt<2><<<dim3(16, 16, 1), blk, 0, stream>>>(dt, dtw_bf, delta, nullptr, dt_bias,
                                                  64, 64, 64, 2048);
  // scan: 3-phase chunked parallel scan
  scan_pq<<<dim3(8, 2, NC), blk, 0, stream>>>(delta, BC, xc, A_log, Pbuf, Qbuf);
  scan_chain<<<dim3(256), blk, 0, stream>>>(Pbuf, Qbuf, Hin);
  scan_y<<<dim3(8, 2, NC), blk, 0, stream>>>(delta, BC, xc, xz, A_log, Dp, Hin, u);
  // GEMM4 (split-K x2): out += u @ out_proj^T  (f32 atomic)
  gemm_nt<4><<<dim3(8, 16, 2), blk, 0, stream>>>(u, wo_bf, (float*)d_out, nullptr, nullptr,
                                                 1024, 2048, 2048, 1024);
}

// Round 4
// 282.855 us; speedup vs baseline: 1.9527x; 1.0607x over previous
//
#include <hip/hip_runtime.h>
#include <hip/hip_bf16.h>
#include <cstdint>

using bf16 = __hip_bfloat16;

typedef short s16x8 __attribute__((ext_vector_type(8)));
typedef float f32x4 __attribute__((ext_vector_type(4)));

#define GLDS16(g, l)                                                                   \
  __builtin_amdgcn_global_load_lds((const __attribute__((address_space(1))) void*)(g), \
                                   (__attribute__((address_space(3))) void*)(l), 16, 0, 0)

__device__ __forceinline__ float bf2f(bf16 v) { return __bfloat162float(v); }
__device__ __forceinline__ bf16  f2bf(float v) { return __float2bfloat16(v); }

#define NC 32   // scan chunks over L
#define CL 32   // chunk length (NC*CL = 1024 = L)

// ---------------- fused f32->bf16 converts + x_proj pad (one launch) ------------------
// ranges: [0,2M) x | [2M,6M) in_proj | [6M,8M) out_proj | [8M,8M+128K) dt_proj
//         [8.125M, 8.125M+256K) wpad (96*2048 real + zero tail)
__global__ void cvt_all_k(const float* __restrict__ x, const float* __restrict__ w1,
                          const float* __restrict__ wo, const float* __restrict__ dtw,
                          const float* __restrict__ xp_w,
                          bf16* __restrict__ x_bf, bf16* __restrict__ w1_bf,
                          bf16* __restrict__ wo_bf, bf16* __restrict__ dtw_bf,
                          bf16* __restrict__ wpad)
{
  const int idx = blockIdx.x * 256 + threadIdx.x;
  if (idx < 2097152) {
    x_bf[idx] = f2bf(x[idx]);
  } else if (idx < 6291456) {
    const int i = idx - 2097152; w1_bf[i] = f2bf(w1[i]);
  } else if (idx < 8388608) {
    const int i = idx - 6291456; wo_bf[i] = f2bf(wo[i]);
  } else if (idx < 8519680) {
    const int i = idx - 8388608; dtw_bf[i] = f2bf(dtw[i]);
  } else if (idx < 8781824) {
    const int i = idx - 8519680;
    wpad[i] = (i < 196608) ? f2bf(xp_w[i]) : f2bf(0.f);
  }
}

// ---------------- generic 128x128 MFMA NT-GEMM: C[m,n] = sum_k A[m,k]*W[n,k] ----------
// K = per-slice K length; blockIdx.z selects K-slice.
// EPI 0: bf16 store   EPI 2: softplus(v+bias[col]) -> f32
// EPI 5: f32 store to slice buffer C0 + z*sstride
template <int EPI>
__global__ __launch_bounds__(256, 2) void gemm_nt(
    const bf16* __restrict__ A, const bf16* __restrict__ W,
    void* __restrict__ C0, const float* __restrict__ bias,
    int K, int lda, int ldb, int ldc, int sstride)
{
  __shared__ __align__(16) bf16 As[128 * 32];
  __shared__ __align__(16) bf16 Bs[128 * 32];

  const int tid  = threadIdx.x;
  const int lane = tid & 63;
  const int wave = tid >> 6;
  const int m0 = blockIdx.y * 128;
  const int n0 = blockIdx.x * 128;
  const int kbase = blockIdx.z * K;
  const int wm = (wave >> 1) * 64;
  const int wn = (wave & 1) * 64;
  const int fr = lane & 15;
  const int fq = lane >> 4;
  const int srow = tid >> 2;
  const int scol = (tid & 3) * 8;

  f32x4 acc[4][4] = {};

  for (int k0 = kbase; k0 < kbase + K; k0 += 32) {
    __syncthreads();
    GLDS16(A + (size_t)(m0 + srow) * lda + (k0 + scol),      As + tid * 8);
    GLDS16(A + (size_t)(m0 + 64 + srow) * lda + (k0 + scol), As + (tid + 256) * 8);
    GLDS16(W + (size_t)(n0 + srow) * ldb + (k0 + scol),      Bs + tid * 8);
    GLDS16(W + (size_t)(n0 + 64 + srow) * ldb + (k0 + scol), Bs + (tid + 256) * 8);
    __syncthreads();

    s16x8 af[4], wf[4];
#pragma unroll
    for (int i = 0; i < 4; ++i) {
      af[i] = *reinterpret_cast<const s16x8*>(As + (wm + i * 16 + fr) * 32 + fq * 8);
      wf[i] = *reinterpret_cast<const s16x8*>(Bs + (wn + i * 16 + fr) * 32 + fq * 8);
    }
#pragma unroll
    for (int i = 0; i < 4; ++i)
#pragma unroll
      for (int j = 0; j < 4; ++j)
        acc[i][j] = __builtin_amdgcn_mfma_f32_16x16x32_bf16(af[i], wf[j], acc[i][j], 0, 0, 0);
  }

#pragma unroll
  for (int i = 0; i < 4; ++i)
#pragma unroll
    for (int j = 0; j < 4; ++j)
#pragma unroll
      for (int r = 0; r < 4; ++r) {
        const int row = m0 + wm + i * 16 + fq * 4 + r;
        const int col = n0 + wn + j * 16 + fr;
        const float v = acc[i][j][r];
        if constexpr (EPI == 0) {
          ((bf16*)C0)[(size_t)row * ldc + col] = f2bf(v);
        } else if constexpr (EPI == 2) {
          const float xb = v + bias[col];
          ((float*)C0)[(size_t)row * ldc + col] =
              fmaxf(xb, 0.f) + log1pf(__expf(-fabsf(xb)));
        } else {
          ((float*)C0)[(size_t)blockIdx.z * sstride + (size_t)row * ldc + col] = v;
        }
      }
}

// ---------------- sum 8 dBC slices -> dt bf16 [2048][64] + BC f32 [2048][32] ----------
__global__ void dbc_reduce_k(const float* __restrict__ dBCs, bf16* __restrict__ dt,
                             float* __restrict__ BC)
{
  const int idx = blockIdx.x * 256 + threadIdx.x;   // 2048*128
  const int row = idx >> 7, col = idx & 127;
  float v = 0.f;
#pragma unroll
  for (int s = 0; s < 8; ++s) v += dBCs[(size_t)s * 262144 + idx];
  if (col < 64)      dt[row * 64 + col] = f2bf(v);
  else if (col < 96) BC[row * 32 + (col - 64)] = v;
}

// ---------------- sum 2 GEMM4 slices -> f32 d_out -------------------------------------
__global__ void g4_reduce_k(const float* __restrict__ G4s, float* __restrict__ out)
{
  const int idx = blockIdx.x * 256 + threadIdx.x;   // 2M
  out[idx] = G4s[idx] + G4s[idx + 2097152];
}

// ---------------- depthwise causal conv K=4 + SiLU: xz(bf16) -> xc(bf16) --------------
__global__ void conv_silu_k(const bf16* __restrict__ xz, const float* __restrict__ cw,
                            bf16* __restrict__ xc)
{
  const int idx = blockIdx.x * 256 + threadIdx.x;   // over B*L*ED = 4M
  const int e  = idx & 2047;
  const int bl = idx >> 11;
  const int l  = bl & 1023;
  const bf16* xp = xz + (size_t)bl * 4096 + e;
  float s = cw[e * 4 + 3] * bf2f(xp[0]);
  if (l >= 1) s += cw[e * 4 + 2] * bf2f(xp[-4096]);
  if (l >= 2) s += cw[e * 4 + 1] * bf2f(xp[-8192]);
  if (l >= 3) s += cw[e * 4 + 0] * bf2f(xp[-12288]);
  xc[idx] = f2bf(s / (1.f + __expf(-s)));
}

// ---------------- scan phase A: per-chunk P[n], q[n] (lane = one channel e) -----------
__global__ __launch_bounds__(256) void scan_pq(
    const float* __restrict__ delta, const float* __restrict__ BC,
    const bf16* __restrict__ xc, const float* __restrict__ A_log,
    float* __restrict__ Pbuf, float* __restrict__ Qbuf)
{
  const int tid = threadIdx.x;
  const int e = blockIdx.x * 256 + tid;
  const int b = blockIdx.y;
  const int c = blockIdx.z;
  const int l0 = c * CL;

  __shared__ float sB[CL * 16];
  for (int i = tid; i < CL * 16; i += 256)
    sB[i] = BC[((size_t)b * 1024 + l0 + (i >> 4)) * 32 + (i & 15)];
  __syncthreads();

  float a2[16], h[16];
#pragma unroll
  for (int n = 0; n < 16; ++n) {
    a2[n] = -__expf(A_log[e * 16 + n]) * 1.44269504f;
    h[n] = 0.f;
  }
  float sumdv = 0.f;

  for (int sub = 0; sub < CL / 16; ++sub) {
    float dreg[16], xreg[16];
#pragma unroll
    for (int tt = 0; tt < 16; ++tt) {
      const size_t row = (size_t)b * 1024 + l0 + sub * 16 + tt;
      dreg[tt] = delta[row * 2048 + e];
      xreg[tt] = bf2f(xc[row * 2048 + e]);
    }
#pragma unroll
    for (int tt = 0; tt < 16; ++tt) {
      const float dv = dreg[tt];
      const float bx = dv * xreg[tt];
      sumdv += dv;
      const int t = sub * 16 + tt;
#pragma unroll
      for (int n = 0; n < 16; ++n)
        h[n] = fmaf(exp2f(dv * a2[n]), h[n], bx * sB[t * 16 + n]);
    }
  }

  const size_t base = (((size_t)b * NC + c) * 2048 + e) * 16;
#pragma unroll
  for (int n = 0; n < 16; ++n) {
    Pbuf[base + n] = exp2f(a2[n] * sumdv);
    Qbuf[base + n] = h[n];
  }
}

// ---------------- scan phase B: sequential combine over NC chunks ---------------------
__global__ __launch_bounds__(256) void scan_chain(
    const float* __restrict__ Pbuf, const float* __restrict__ Qbuf,
    float* __restrict__ Hin)
{
  const int idx = blockIdx.x * 256 + threadIdx.x;   // (b*2048+e)*16+n
  const int b = idx >> 15;
  const int rem = idx & 32767;
  float h = 0.f;
  for (int c = 0; c < NC; ++c) {
    const size_t base = ((size_t)(b * NC + c)) * 32768 + rem;
    Hin[base] = h;
    h = fmaf(Pbuf[base], h, Qbuf[base]);
  }
}

// ---------------- scan phase C: recompute chunk scan from Hin, emit u -----------------
__global__ __launch_bounds__(256) void scan_y(
    const float* __restrict__ delta, const float* __restrict__ BC,
    const bf16* __restrict__ xc, const bf16* __restrict__ xz,
    const float* __restrict__ A_log, const float* __restrict__ Dp,
    const float* __restrict__ Hin, bf16* __restrict__ u)
{
  const int tid = threadIdx.x;
  const int e = blockIdx.x * 256 + tid;
  const int b = blockIdx.y;
  const int c = blockIdx.z;
  const int l0 = c * CL;

  __shared__ float sBC[CL * 32];
  for (int i = tid; i < CL * 32; i += 256)
    sBC[i] = BC[((size_t)b * 1024 + l0 + (i >> 5)) * 32 + (i & 31)];
  __syncthreads();

  float a2[16], h[16];
  const size_t hbase = (((size_t)b * NC + c) * 2048 + e) * 16;
#pragma unroll
  for (int n = 0; n < 16; ++n) {
    a2[n] = -__expf(A_log[e * 16 + n]) * 1.44269504f;
    h[n] = Hin[hbase + n];
  }
  const float D_e = Dp[e];

  for (int sub = 0; sub < CL / 16; ++sub) {
    float dreg[16], xreg[16], zreg[16];
#pragma unroll
    for (int tt = 0; tt < 16; ++tt) {
      const size_t row = (size_t)b * 1024 + l0 + sub * 16 + tt;
      dreg[tt] = delta[row * 2048 + e];
      xreg[tt] = bf2f(xc[row * 2048 + e]);
      zreg[tt] = bf2f(xz[row * 4096 + 2048 + e]);
    }
#pragma unroll
    for (int tt = 0; tt < 16; ++tt) {
      const float dv = dreg[tt];
      const float xcv = xreg[tt];
      const float bx = dv * xcv;
      const int t = sub * 16 + tt;
      float y0 = 0.f, y1 = 0.f, y2 = 0.f, y3 = 0.f;
#pragma unroll
      for (int n = 0; n < 16; ++n) {
        h[n] = fmaf(exp2f(dv * a2[n]), h[n], bx * sBC[t * 32 + n]);
        const float cv = sBC[t * 32 + 16 + n];
        if ((n & 3) == 0)      y0 = fmaf(h[n], cv, y0);
        else if ((n & 3) == 1) y1 = fmaf(h[n], cv, y1);
        else if ((n & 3) == 2) y2 = fmaf(h[n], cv, y2);
        else                   y3 = fmaf(h[n], cv, y3);
      }
      const float y = ((y0 + y1) + (y2 + y3)) + D_e * xcv;
      const float zv = zreg[tt];
      const size_t row = (size_t)b * 1024 + l0 + t;
      u[row * 2048 + e] = f2bf(y * (zv / (1.f + __expf(-zv))));
    }
  }
}

extern "C" void kernel_launch(void* const* d_in, const int* in_sizes, int n_in,
                              void* d_out, int out_size, void* d_ws, size_t ws_size,
                              hipStream_t stream)
{
  (void)in_sizes; (void)n_in; (void)out_size; (void)ws_size;
  const float* x        = (const float*)d_in[0];   // (2,1024,1024)
  const float* in_proj  = (const float*)d_in[1];   // (4096,1024)
  const float* conv_w   = (const float*)d_in[2];   // (2048,1,4)
  const float* x_proj   = (const float*)d_in[3];   // (96,2048)
  const float* dt_proj  = (const float*)d_in[4];   // (2048,64)
  const float* dt_bias  = (const float*)d_in[5];   // (2048,)
  const float* A_log    = (const float*)d_in[6];   // (2048,16)
  const float* Dp       = (const float*)d_in[7];   // (2048,)
  const float* out_proj = (const float*)d_in[8];   // (1024,2048)

  char* ws = (char*)d_ws;                          // ~119 MB used (ws = 256 MiB)
  bf16*  xz     = (bf16*) (ws);                    // 2048 x 4096 bf16 (xp | z)
  bf16*  xc     = (bf16*) (ws + 16777216);         // 2048 x 2048 bf16
  bf16*  dt     = (bf16*) (ws + 25165824);         // 2048 x 64 bf16
  float* BC     = (float*)(ws + 25427968);         // 2048 x 32 f32 (Bm|Cm)
  float* delta  = (float*)(ws + 25690112);         // 2048 x 2048 f32
  bf16*  u      = (bf16*) (ws + 42467328);         // 2048 x 2048 bf16
  bf16*  wpad   = (bf16*) (ws + 50855936);         // 128 x 2048 bf16
  bf16*  x_bf   = (bf16*) (ws + 51380224);         // 2048 x 1024 bf16
  bf16*  w1_bf  = (bf16*) (ws + 55574528);         // 4096 x 1024 bf16
  bf16*  wo_bf  = (bf16*) (ws + 63963136);         // 1024 x 2048 bf16
  bf16*  dtw_bf = (bf16*) (ws + 68157440);         // 2048 x 64 bf16
  float* dBCs   = (float*)(ws + 68419584);         // 8 x 2048 x 128 f32 slices
  float* G4s    = (float*)(ws + 76808192);         // 2 x 2M f32 slices
  float* Pbuf   = (float*)(ws + 93585408);         // 8.4 MB
  float* Qbuf   = (float*)(ws + 101974016);        // 8.4 MB
  float* Hin    = (float*)(ws + 110362624);        // 8.4 MB (end 118,751,232)

  dim3 blk(256);

  // all f32->bf16 conversions + x_proj pad in one launch
  cvt_all_k<<<dim3(34304), blk, 0, stream>>>(x, in_proj, out_proj, dt_proj, x_proj,
                                             x_bf, w1_bf, wo_bf, dtw_bf, wpad);
  // GEMM1: xz = x @ in_proj^T   (bf16 out)
  gemm_nt<0><<<dim3(32, 16, 1), blk, 0, stream>>>(x_bf, w1_bf, xz, nullptr,
                                                  1024, 1024, 1024, 4096, 0);
  // conv + silu -> xc (bf16)
  conv_silu_k<<<dim3(16384), blk, 0, stream>>>(xz, conv_w, xc);
  // GEMM2 (split-K x8, per-slice stores): dBCs[z] = xc @ wpad^T slice
  gemm_nt<5><<<dim3(1, 16, 8), blk, 0, stream>>>(xc, wpad, dBCs, nullptr,
                                                 256, 2048, 2048, 128, 262144);
  dbc_reduce_k<<<dim3(1024), blk, 0, stream>>>(dBCs, dt, BC);
  // GEMM3: delta = softplus(dt @ dt_proj^T + b)  (f32)
  gemm_nt<2><<<dim3(16, 16, 1), blk, 0, stream>>>(dt, dtw_bf, delta, dt_bias,
                                                  64, 64, 64, 2048, 0);
  // scan: 3-phase chunked parallel scan
  scan_pq<<<dim3(8, 2, NC), blk, 0, stream>>>(delta, BC, xc, A_log, Pbuf, Qbuf);
  scan_chain<<<dim3(256), blk, 0, stream>>>(Pbuf, Qbuf, Hin);
  scan_y<<<dim3(8, 2, NC), blk, 0, stream>>>(delta, BC, xc, xz, A_log, Dp, Hin, u);
  // GEMM4 (split-K x2, per-slice stores): G4s[z] = u @ out_proj^T slice
  gemm_nt<5><<<dim3(8, 16, 2), blk, 0, stream>>>(u, wo_bf, G4s, nullptr,
                                                 1024, 2048, 2048, 1024, 2097152);
  g4_reduce_k<<<dim3(8192), blk, 0, stream>>>(G4s, (float*)d_out);
}